// Round 8
// baseline (152.202 us; speedup 1.0000x reference)
//
#include <hip/hip_runtime.h>
#include <hip/hip_cooperative_groups.h>

namespace cg = cooperative_groups;

// ConcatCritic: scores[i,j] = W2 . relu(x_i@W1x + y_j@W1y + b1) + b2
// B=512, DIM_X=DIM_Y=128, HIDDEN=512. fp32 in/out.
//
// R8 = R7 + store-index fix: partial store was missing the j0/2 column
// offset (the actual cause of R6 AND R7 failures — not fence semantics).
// ONE cooperative kernel (256 blocks x 512 thr), 3 phases with grid.sync().

#define BATCH 512
#define DX    128
#define HID   512

#define TI   128
#define TJ   64
#define HPW  32          // half2 per h-chunk (64 h)
#define ST   33          // uint stride per LDS row

typedef _Float16 half2_t __attribute__((ext_vector_type(2)));

static __device__ __forceinline__ half2_t u2h(unsigned int u) {
    union { unsigned int u; half2_t h; } c; c.u = u; return c.h;
}
static __device__ __forceinline__ unsigned int h2u(half2_t h) {
    union { half2_t h; unsigned int u; } c; c.h = h; return c.u;
}

__global__ __launch_bounds__(512, 2) void fused_kernel(
    const float* __restrict__ x, const float* __restrict__ y,
    const float* __restrict__ W1, const float* __restrict__ b1,
    const float* __restrict__ W2, const float* __restrict__ b2,
    float* __restrict__ out, _Float16* __restrict__ hxy,
    unsigned int* __restrict__ pws16)
{
    cg::grid_group grid = cg::this_grid();
    const int b   = blockIdx.x;
    const int tid = threadIdx.x;

    __shared__ float        sProj[8][DX];        //  4 KiB (phase 1)
    __shared__ unsigned int sA[TI * ST];         // 16.9 KiB (phase 2)
    __shared__ unsigned int sB[TJ * ST];         //  8.5 KiB
    __shared__ unsigned int sW[HPW];

    // ================= Phase 1: projection =================
    // block b: part = b>>7, row-group = (b&127)>>1 (8 rows), h-half = b&1.
    {
        const int part = b >> 7;
        const int row0 = ((b & 127) >> 1) * 8;
        const int h0   = (b & 1) * 256;
        const float* __restrict__ src = part ? y : x;
        const float* __restrict__ W   = W1 + part * DX * HID;

        if (tid < 256) {                         // 8 rows x 128 f32 = 256 float4
            const int r = tid >> 5, c4 = (tid & 31) << 2;
            const float4 v = *(const float4*)&src[(row0 + r) * DX + c4];
            sProj[r][c4]     = v.x; sProj[r][c4 + 1] = v.y;
            sProj[r][c4 + 2] = v.z; sProj[r][c4 + 3] = v.w;
        }
        __syncthreads();

        const int h     = h0 + (tid & 255);
        const int rbase = (tid >> 8) * 4;
        float acc[4] = {0.f, 0.f, 0.f, 0.f};
        #pragma unroll 8
        for (int k = 0; k < DX; ++k) {
            const float w = W[k * HID + h];      // coalesced across threads
            #pragma unroll
            for (int r = 0; r < 4; ++r) acc[r] = fmaf(sProj[rbase + r][k], w, acc[r]);
        }
        const float bias = part ? b1[h] : 0.0f;
        #pragma unroll
        for (int r = 0; r < 4; ++r)
            hxy[(part * BATCH + row0 + rbase + r) * HID + h] = (_Float16)(acc[r] + bias);
    }

    grid.sync();

    // ================= Phase 2: score partials =================
    // b -> (it, jt, z): z = b&7, jt = (b>>3)&7, it = b>>6.
    {
        const int z   = b & 7;
        const int j0  = ((b >> 3) & 7) * TJ;
        const int i0  = (b >> 6) * TI;
        const int hp0 = z * HPW;                 // in half2 units
        const unsigned int* __restrict__ hx32 = (const unsigned int*)hxy; // [row][256 hp]

        #pragma unroll
        for (int it = 0; it < 2; ++it) {         // sA: 1024 uint4 slots
            const int s = tid + it * 512;
            const int row = s >> 3, q = s & 7;
            const uint4 v = *(const uint4*)&hx32[(i0 + row) * 256 + hp0 + (q << 2)];
            unsigned int* p = &sA[row * ST + (q << 2)];
            p[0] = v.x; p[1] = v.y; p[2] = v.z; p[3] = v.w;
        }
        {                                        // sB: 512 uint4 slots
            const int row = tid >> 3, q = tid & 7;
            const uint4 v = *(const uint4*)&hx32[(BATCH + j0 + row) * 256 + hp0 + (q << 2)];
            unsigned int* p = &sB[row * ST + (q << 2)];
            p[0] = v.x; p[1] = v.y; p[2] = v.z; p[3] = v.w;
        }
        if (tid < HPW) {
            const float2 w = *(const float2*)&W2[2 * (hp0 + tid)];
            half2_t wh; wh.x = (_Float16)w.x; wh.y = (_Float16)w.y;
            sW[tid] = h2u(wh);
        }
        __syncthreads();

        const int tx = tid & 15;                 // 4 cols each -> 64
        const int ty = tid >> 4;                 // 4 rows each -> 128
        const unsigned int* pa = &sA[(ty << 2) * ST];
        const unsigned int* pb = &sB[(tx << 2) * ST];

        float acc[4][4] = {{0.f,0.f,0.f,0.f},{0.f,0.f,0.f,0.f},
                           {0.f,0.f,0.f,0.f},{0.f,0.f,0.f,0.f}};
        const half2_t hz = {(_Float16)0, (_Float16)0};

        #pragma unroll 4
        for (int hp = 0; hp < HPW; ++hp) {
            const half2_t w = u2h(sW[hp]);
            half2_t a[4], bb[4];
            #pragma unroll
            for (int r = 0; r < 4; ++r) a[r]  = u2h(pa[r * ST + hp]);
            #pragma unroll
            for (int c = 0; c < 4; ++c) bb[c] = u2h(pb[c * ST + hp]);
            #pragma unroll
            for (int r = 0; r < 4; ++r)
                #pragma unroll
                for (int c = 0; c < 4; ++c) {
                    half2_t t = a[r] + bb[c];                  // v_pk_add_f16
                    t = __builtin_elementwise_max(t, hz);      // v_pk_max_f16
                    acc[r][c] = __builtin_amdgcn_fdot2(t, w, acc[r][c], false);
                }
        }

        // f16 partial store: slice z, coalesced uint2 (j0/2 offset FIXED)
        const int i = i0 + (ty << 2);
        unsigned int* dst = pws16 + z * (BATCH * BATCH / 2);
        #pragma unroll
        for (int r = 0; r < 4; ++r) {
            half2_t p0, p1;
            p0.x = (_Float16)acc[r][0]; p0.y = (_Float16)acc[r][1];
            p1.x = (_Float16)acc[r][2]; p1.y = (_Float16)acc[r][3];
            uint2 st; st.x = h2u(p0); st.y = h2u(p1);
            *(uint2*)&dst[(i + r) * (BATCH / 2) + (j0 >> 1) + (tx << 1)] = st;
        }
    }

    grid.sync();

    // ================= Phase 3: reduce 8 slices + b2 =================
    // 131072 threads, one uint (2 cells) each; coalesced reads per slice.
    {
        const int gid = b * 512 + tid;
        float s0 = 0.f, s1 = 0.f;
        #pragma unroll
        for (int zz = 0; zz < 8; ++zz) {
            const half2_t v = u2h(pws16[zz * (BATCH * BATCH / 2) + gid]);
            s0 += (float)v.x; s1 += (float)v.y;
        }
        const float bs = b2[0];
        *(float2*)&out[gid * 2] = make_float2(s0 + bs, s1 + bs);
    }
}

extern "C" void kernel_launch(void* const* d_in, const int* in_sizes, int n_in,
                              void* d_out, int out_size, void* d_ws, size_t ws_size,
                              hipStream_t stream) {
    const float* x  = (const float*)d_in[0];
    const float* y  = (const float*)d_in[1];
    const float* W1 = (const float*)d_in[2];
    const float* b1 = (const float*)d_in[3];
    const float* W2 = (const float*)d_in[4];
    const float* b2 = (const float*)d_in[5];
    float* out = (float*)d_out;

    _Float16* hxy       = (_Float16*)d_ws;                          // 1 MiB
    unsigned int* pws16 = (unsigned int*)((char*)d_ws + (1 << 20)); // 4 MiB

    void* args[] = {
        (void*)&x, (void*)&y, (void*)&W1, (void*)&b1, (void*)&W2, (void*)&b2,
        (void*)&out, (void*)&hxy, (void*)&pws16
    };
    (void)hipLaunchCooperativeKernel((void*)fused_kernel, dim3(256), dim3(512),
                                     args, 0, stream);
}

// Round 9
// 84.633 us; speedup vs baseline: 1.7984x; 1.7984x over previous
//
#include <hip/hip_runtime.h>

// ConcatCritic: scores[i,j] = W2 . relu(x_i@W1x + y_j@W1y + b1) + b2
// B=512, DIM_X=DIM_Y=128, HIDDEN=512. fp32 in/out.
//
// R9 = R5 structure (3 kernels — fastest verified: 88.7 µs) + f16 partials
// (validated in R8 at absmax 0.0156). Cooperative/grid.sync variant (R8)
// cost +60 µs of barrier spin — reverted. Manual fence split-K (R6) — dead.
//
// proj:   fp32 math -> f16 hxy ws. 256 blocks.
// score:  128(i) x 64(j) tile, 512 thr, 4x4 cells/thread, z=8 h-chunks,
//         f16 partial slices (4 MB total). 256 blocks x 8 waves.
// reduce: sum 8 f16 slices + b2 -> fp32 out. 512 blocks.

#define BATCH 512
#define DX    128
#define HID   512

typedef _Float16 half2_t __attribute__((ext_vector_type(2)));

static __device__ __forceinline__ half2_t u2h(unsigned int u) {
    union { unsigned int u; half2_t h; } c; c.u = u; return c.h;
}
static __device__ __forceinline__ unsigned int h2u(half2_t h) {
    union { half2_t h; unsigned int u; } c; c.h = h; return c.u;
}

// ---------------- Kernel A: projection (fp32 math, f16 out) ----------------
__global__ __launch_bounds__(256) void proj_kernel(
    const float* __restrict__ x, const float* __restrict__ y,
    const float* __restrict__ W1, const float* __restrict__ b1,
    _Float16* __restrict__ hxy)
{
    const int part = blockIdx.y;                 // 0 -> x, 1 -> y
    const int row0 = blockIdx.x * 8;
    const int h    = blockIdx.z * 256 + threadIdx.x;
    const float* __restrict__ src = part ? y : x;
    const float* __restrict__ W   = W1 + part * DX * HID;

    __shared__ float s[8][DX];
    {
        const int t = threadIdx.x;               // 256 float4 slots
        const int r = t >> 5, c4 = (t & 31) << 2;
        const float4 v = *(const float4*)&src[(row0 + r) * DX + c4];
        s[r][c4] = v.x; s[r][c4 + 1] = v.y; s[r][c4 + 2] = v.z; s[r][c4 + 3] = v.w;
    }
    __syncthreads();

    float acc[8] = {0.f, 0.f, 0.f, 0.f, 0.f, 0.f, 0.f, 0.f};
    #pragma unroll 8
    for (int k = 0; k < DX; ++k) {
        const float w = W[k * HID + h];          // coalesced across threads
        #pragma unroll
        for (int r = 0; r < 8; ++r) acc[r] = fmaf(s[r][k], w, acc[r]);
    }
    const float bias = part ? b1[h] : 0.0f;
    #pragma unroll
    for (int r = 0; r < 8; ++r)
        hxy[(part * BATCH + row0 + r) * HID + h] = (_Float16)(acc[r] + bias);
}

// ---------------- Kernel B: score partials ----------------
#define TI   128
#define TJ   64
#define HPW  32          // half2 per 64-h chunk
#define ST   33          // uint stride per LDS row (odd -> conflict-free)

__global__ __launch_bounds__(512, 2) void score_kernel(
    const _Float16* __restrict__ hxy, const float* __restrict__ W2,
    unsigned int* __restrict__ pws16)
{
    __shared__ unsigned int sA[TI * ST];         // 16.9 KiB
    __shared__ unsigned int sB[TJ * ST];         //  8.5 KiB
    __shared__ unsigned int sW[HPW];

    const int i0  = blockIdx.y * TI;
    const int j0  = blockIdx.x * TJ;
    const int z   = blockIdx.z;
    const int hp0 = z * HPW;                     // in half2 units
    const int tid = threadIdx.x;
    const unsigned int* __restrict__ hx32 = (const unsigned int*)hxy; // [row][256 hp]

    #pragma unroll
    for (int it = 0; it < 2; ++it) {             // sA: 1024 uint4 slots
        const int s = tid + it * 512;
        const int row = s >> 3, q = s & 7;
        const uint4 v = *(const uint4*)&hx32[(i0 + row) * 256 + hp0 + (q << 2)];
        unsigned int* p = &sA[row * ST + (q << 2)];
        p[0] = v.x; p[1] = v.y; p[2] = v.z; p[3] = v.w;
    }
    {                                            // sB: 512 uint4 slots
        const int row = tid >> 3, q = tid & 7;
        const uint4 v = *(const uint4*)&hx32[(BATCH + j0 + row) * 256 + hp0 + (q << 2)];
        unsigned int* p = &sB[row * ST + (q << 2)];
        p[0] = v.x; p[1] = v.y; p[2] = v.z; p[3] = v.w;
    }
    if (tid < HPW) {
        const float2 w = *(const float2*)&W2[2 * (hp0 + tid)];
        half2_t wh; wh.x = (_Float16)w.x; wh.y = (_Float16)w.y;
        sW[tid] = h2u(wh);
    }
    __syncthreads();

    const int tx = tid & 15;                     // 4 cols each -> 64
    const int ty = tid >> 4;                     // 4 rows each -> 128
    const unsigned int* pa = &sA[(ty << 2) * ST];
    const unsigned int* pb = &sB[(tx << 2) * ST];

    float acc[4][4] = {{0.f,0.f,0.f,0.f},{0.f,0.f,0.f,0.f},
                       {0.f,0.f,0.f,0.f},{0.f,0.f,0.f,0.f}};
    const half2_t hz = {(_Float16)0, (_Float16)0};

    #pragma unroll 4
    for (int hp = 0; hp < HPW; ++hp) {
        const half2_t w = u2h(sW[hp]);
        half2_t a[4], bb[4];
        #pragma unroll
        for (int r = 0; r < 4; ++r) a[r]  = u2h(pa[r * ST + hp]);
        #pragma unroll
        for (int c = 0; c < 4; ++c) bb[c] = u2h(pb[c * ST + hp]);
        #pragma unroll
        for (int r = 0; r < 4; ++r)
            #pragma unroll
            for (int c = 0; c < 4; ++c) {
                half2_t t = a[r] + bb[c];                  // v_pk_add_f16
                t = __builtin_elementwise_max(t, hz);      // v_pk_max_f16
                acc[r][c] = __builtin_amdgcn_fdot2(t, w, acc[r][c], false);
            }
    }

    // ---- f16 partial store: slice z, coalesced uint2 (with j0/2 offset)
    const int i = i0 + (ty << 2);
    unsigned int* dst = pws16 + z * (BATCH * BATCH / 2);
    #pragma unroll
    for (int r = 0; r < 4; ++r) {
        half2_t p0, p1;
        p0.x = (_Float16)acc[r][0]; p0.y = (_Float16)acc[r][1];
        p1.x = (_Float16)acc[r][2]; p1.y = (_Float16)acc[r][3];
        uint2 st; st.x = h2u(p0); st.y = h2u(p1);
        *(uint2*)&dst[(i + r) * (BATCH / 2) + (j0 >> 1) + (tx << 1)] = st;
    }
}

// ---------------- Kernel C: reduce 8 f16 slices + b2 ----------------
__global__ __launch_bounds__(256) void reduce_kernel(
    const unsigned int* __restrict__ pws16, const float* __restrict__ b2,
    float* __restrict__ out)
{
    const int gid = blockIdx.x * 256 + threadIdx.x;      // 0..131071 uints
    float s0 = 0.f, s1 = 0.f;
    #pragma unroll
    for (int zz = 0; zz < 8; ++zz) {
        const half2_t v = u2h(pws16[zz * (BATCH * BATCH / 2) + gid]);
        s0 += (float)v.x; s1 += (float)v.y;
    }
    const float bs = b2[0];
    *(float2*)&out[gid * 2] = make_float2(s0 + bs, s1 + bs);
}

extern "C" void kernel_launch(void* const* d_in, const int* in_sizes, int n_in,
                              void* d_out, int out_size, void* d_ws, size_t ws_size,
                              hipStream_t stream) {
    const float* x  = (const float*)d_in[0];
    const float* y  = (const float*)d_in[1];
    const float* W1 = (const float*)d_in[2];
    const float* b1 = (const float*)d_in[3];
    const float* W2 = (const float*)d_in[4];
    const float* b2 = (const float*)d_in[5];
    float* out = (float*)d_out;

    _Float16* hxy       = (_Float16*)d_ws;                          // 1 MiB
    unsigned int* pws16 = (unsigned int*)((char*)d_ws + (1 << 20)); // 4 MiB

    proj_kernel<<<dim3(BATCH / 8, 2, 2), 256, 0, stream>>>(x, y, W1, b1, hxy);
    score_kernel<<<dim3(BATCH / TJ, BATCH / TI, 8), 512, 0, stream>>>(hxy, W2, pws16);
    reduce_kernel<<<dim3(BATCH * BATCH / 2 / 256), 256, 0, stream>>>(pws16, b2, out);
}